// Round 21
// baseline (244.001 us; speedup 1.0000x reference)
//
#include <hip/hip_runtime.h>
#include <math.h>

#define DEV static __device__ __forceinline__

// ---------------- 4-qubit real-amplitude circuit helpers ----------------
template <int W>
DEV void q_ry(float s[16], float th) {
  float c = cosf(th * 0.5f), sn = sinf(th * 0.5f);
  constexpr int m = 8 >> W;
#pragma unroll
  for (int i = 0; i < 16; ++i) {
    if (!(i & m)) {
      float a = s[i], b = s[i | m];
      s[i] = c * a - sn * b;
      s[i | m] = sn * a + c * b;
    }
  }
}
template <int C, int T>
DEV void q_cnot(float s[16]) {
  constexpr int mc = 8 >> C, mt = 8 >> T;
#pragma unroll
  for (int i = 0; i < 16; ++i) {
    if ((i & mc) && !(i & mt)) {
      float t = s[i]; s[i] = s[i | mt]; s[i | mt] = t;
    }
  }
}
template <int W>
DEV float q_mz(const float s[16]) {
  constexpr int m = 8 >> W;
  float p = 0.f;
#pragma unroll
  for (int i = 0; i < 16; ++i) p += (i & m) ? -s[i] * s[i] : s[i] * s[i];
  return p;
}
DEV void q_layer(float s[16], const float* __restrict__ th) {
  q_ry<0>(s, th[0]); q_cnot<0, 1>(s);
  q_ry<1>(s, th[1]); q_cnot<1, 2>(s);
  q_ry<2>(s, th[2]); q_cnot<2, 3>(s);
  q_ry<3>(s, th[3]); q_cnot<3, 0>(s);
}

// ---------------- weight reorder pre-kernel (conv1 only) ----------------
__global__ void k_wre(const float* __restrict__ c1w, float* __restrict__ wre1) {
  int t = blockIdx.x * 256 + threadIdx.x;
  if (t < 450) {
    int g = t / 30, rem = t % 30;
    int ci = g / 5, ky = g % 5, kx = rem / 6, co = rem % 6;
    wre1[t] = c1w[co * 75 + ci * 25 + ky * 5 + kx];
  }
}

// row base with parity rotation
DEV int c1_rowbase(int row) { return row * 39 + ((row >> 1) & 1); }

// ---------------- conv1 (5x5 s2 p1, 3->6) + relu + pool(2x2 s1) ----------------
// v10: v8 compute (proven) + INCREMENTAL staging addresses — thread owns one
// column (row0=tid/39, cc fixed), walks rows in steps of 6: iy+=6, base+=234,
// rot^=1 (exact: ((row0+6s)>>1)&1 = rot0^(s&1)). cc/ix checks hoisted.
// No new live registers (v7/v9 lesson: budget is exactly full at 60 VGPR).
// x: (128,3,249,249) -> pooled out: (128,6,123,[128])
__global__ __launch_bounds__(256, 4) void k_conv1(const float* __restrict__ x,
                                                  const float* __restrict__ wre1,
                                                  const float* __restrict__ bia,
                                                  float* __restrict__ out) {
  __shared__ float smem[4800];
  float (*ct)[42][19] = (float (*)[42][19])smem;
  int b = blockIdx.z;
  int PY0 = blockIdx.y * 41, PX0 = blockIdx.x * 16;
  int iy0 = PY0 * 2 - 1, ix0 = PX0 * 2 - 1;
  int tid = threadIdx.x;
  const float* xb = x + (size_t)b * 186003;
  int r = tid / 6, seg = tid - 6 * (tid / 6);
  // staging map: fixed column per thread
  int row0 = tid / 39, cc = tid - row0 * 39;    // 234 active lanes
  bool ccok = (tid < 234) && (cc < 37);
  int ixg = ix0 + cc;
  bool ixok = (unsigned)ixg < 249u;
  int rot0 = (row0 >> 1) & 1;
  float acc[6][3];
#pragma unroll
  for (int co = 0; co < 6; ++co) {
    float bv = bia[co];
#pragma unroll
    for (int c = 0; c < 3; ++c) acc[co][c] = bv;
  }
#pragma unroll 1
  for (int ci = 0; ci < 3; ++ci) {
    if (ci) __syncthreads();
    const float* xci = xb + ci * 62001;
    {
      int iy = iy0 + row0;
      int rr = row0;
      int base = row0 * 39 + cc;
      int rot = rot0;
#pragma unroll
      for (int s = 0; s < 15; ++s) {
        if (ccok && rr < 87) {
          float v = 0.f;
          if (ixok && (unsigned)iy < 249u) v = xci[iy * 249 + ixg];
          smem[base + rot] = v;
        }
        iy += 6; rr += 6; base += 234; rot ^= 1;
      }
    }
    __syncthreads();
    if (tid < 252) {
#pragma unroll
      for (int ky = 0; ky < 5; ++ky) {
        const float* xrow = &smem[c1_rowbase(2 * r + ky) + 6 * seg];
        float xv[10];
#pragma unroll
        for (int j = 0; j < 10; ++j) xv[j] = xrow[j];
        const float* wp = wre1 + (ci * 5 + ky) * 30;
        float wr[30];
#pragma unroll
        for (int j = 0; j < 30; ++j) wr[j] = wp[j];
#pragma unroll
        for (int c = 0; c < 3; ++c)
#pragma unroll
          for (int kx = 0; kx < 5; ++kx)
#pragma unroll
            for (int co = 0; co < 6; ++co)
              acc[co][c] += xv[2 * c + kx] * wr[kx * 6 + co];
      }
    }
  }
  __syncthreads();
  if (tid < 252) {
#pragma unroll
    for (int co = 0; co < 6; ++co)
#pragma unroll
      for (int c = 0; c < 3; ++c)
        if (3 * seg + c < 17) ct[co][r][3 * seg + c] = acc[co][c];
  }
  __syncthreads();
#pragma unroll
  for (int co2 = 0; co2 < 6; ++co2) {
    for (int j = tid; j < 41 * 16; j += 256) {
      int pr = j >> 4, pc = j & 15;
      float m = fmaxf(fmaxf(ct[co2][pr][pc], ct[co2][pr][pc + 1]),
                      fmaxf(ct[co2][pr + 1][pc], ct[co2][pr + 1][pc + 1]));
      out[((size_t)(b * 6 + co2) * 123 + PY0 + pr) * 128 + PX0 + pc] = fmaxf(m, 0.f);
    }
  }
}

// ---------------- conv2 (3x3 s2 p1, 6->15) + relu + pool (FROZEN) ----------------
__global__ __launch_bounds__(256, 4) void k_conv2(const float* __restrict__ in,
                                                  const float* __restrict__ w,
                                                  const float* __restrict__ bia,
                                                  float* __restrict__ out) {
  __shared__ float smem[6 * 35 * 36];
  float (*xs)[35][36] = (float (*)[35][36])smem;
  float (*ct)[17][18] = (float (*)[17][18])smem;
  int b = blockIdx.z;
  int py0 = blockIdx.y * 16, px0 = blockIdx.x * 16;
  int iy0 = py0 * 2 - 1, ix0 = px0 * 2 - 1;
  int tid = threadIdx.x;
  const float* ib = in + (size_t)b * 94464;
  for (int idx = tid; idx < 6 * 35 * 36; idx += 256) {
    int ci = idx / 1260, rem = idx % 1260, rr = rem / 36, cc = rem % 36;
    int iy = iy0 + rr, ix = ix0 + cc;
    float v = 0.f;
    if (cc < 35 && (unsigned)iy < 123u && (unsigned)ix < 123u)
      v = ib[ci * 15744 + iy * 128 + ix];
    xs[ci][rr][cc] = v;
  }
  __syncthreads();
  int co = tid % 15, ty = tid / 15;
  float acc[17];
  if (tid < 255) {
    float bv = bia[co];
#pragma unroll
    for (int t = 0; t < 17; ++t) acc[t] = bv;
#pragma unroll
    for (int ci = 0; ci < 6; ++ci) {
      float wreg[9];
#pragma unroll
      for (int j = 0; j < 9; ++j) wreg[j] = w[co * 54 + ci * 9 + j];
#pragma unroll
      for (int ky = 0; ky < 3; ++ky) {
        const float* xrow = &xs[ci][2 * ty + ky][0];
        float xv[36];
#pragma unroll
        for (int j = 0; j < 18; ++j) {
          float2 t2 = *reinterpret_cast<const float2*>(&xrow[2 * j]);
          xv[2 * j] = t2.x; xv[2 * j + 1] = t2.y;
        }
#pragma unroll
        for (int tx = 0; tx < 17; ++tx)
#pragma unroll
          for (int kx = 0; kx < 3; ++kx)
            acc[tx] += xv[2 * tx + kx] * wreg[ky * 3 + kx];
      }
    }
  }
  __syncthreads();
  if (tid < 255) {
#pragma unroll
    for (int tx = 0; tx < 17; ++tx) ct[co][ty][tx] = acc[tx];
  }
  __syncthreads();
  for (int i = tid; i < 15 * 16 * 16; i += 256) {
    int co2 = i / 256, rem = i % 256, pr = rem / 16, pc = rem % 16;
    int py = py0 + pr, px = px0 + pc;
    if (py < 61 && px < 61) {
      float m = fmaxf(fmaxf(ct[co2][pr][pc], ct[co2][pr][pc + 1]),
                      fmaxf(ct[co2][pr + 1][pc], ct[co2][pr + 1][pc + 1]));
      out[(size_t)b * 55815 + co2 * 3721 + py * 61 + px] = fmaxf(m, 0.f);
    }
  }
}

// ---------------- fc1 (round-14 body, 768 blocks — proven round 20) -------------
#define KFC 55815
#define NCHUNK 1745  // ceil(55815/32)
#define FC1_BLOCKS 768
#define RSPLIT 24    // FC1_BLOCKS / 32
__global__ __launch_bounds__(256) void k_fc1(const float* __restrict__ h,
                                             const float* __restrict__ w,
                                             float* __restrict__ partial) {
  __shared__ float hs[128][33];   // +1 pad
  __shared__ float wsd[120][33];
  int tid = threadIdx.x;
  int tb = tid & 31;   // batch lane
  int bo = tid >> 5;   // output group: outputs bo*15 .. bo*15+14
  float acc[4][15];
#pragma unroll
  for (int j = 0; j < 4; ++j)
#pragma unroll
    for (int oo = 0; oo < 15; ++oo) acc[j][oo] = 0.f;

  for (int ch = blockIdx.x; ch < NCHUNK; ch += FC1_BLOCKS) {
    int k0 = ch * 32;
    for (int idx = tid; idx < 128 * 32; idx += 256) {
      int bb = idx >> 5, kk = idx & 31;
      int k = k0 + kk;
      hs[bb][kk] = (k < KFC) ? h[(size_t)bb * KFC + k] : 0.f;
    }
    for (int idx = tid; idx < 120 * 32; idx += 256) {
      int oo = idx >> 5, kk = idx & 31;
      int k = k0 + kk;
      wsd[oo][kk] = (k < KFC) ? w[(size_t)oo * KFC + k] : 0.f;
    }
    __syncthreads();
#pragma unroll 4
    for (int kk = 0; kk < 32; ++kk) {
      float hv[4], wv[15];
#pragma unroll
      for (int j = 0; j < 4; ++j) hv[j] = hs[tb + 32 * j][kk];
#pragma unroll
      for (int oo = 0; oo < 15; ++oo) wv[oo] = wsd[bo * 15 + oo][kk];
#pragma unroll
      for (int j = 0; j < 4; ++j)
#pragma unroll
        for (int oo = 0; oo < 15; ++oo) acc[j][oo] += hv[j] * wv[oo];
    }
    __syncthreads();
  }
  float* pg = partial + (size_t)blockIdx.x * 15360;
#pragma unroll
  for (int j = 0; j < 4; ++j) {
    int b = tb + 32 * j;
#pragma unroll
    for (int oo = 0; oo < 15; ++oo) pg[b * 120 + bo * 15 + oo] = acc[j][oo];
  }
}

// ---------------- fc1 reduce: 2-stage, RSPLIT=24 group-splits -------------------
__global__ __launch_bounds__(256) void k_reduceA(const float* __restrict__ partial,
                                                 float* __restrict__ partial2) {
  int gs = blockIdx.x / 60;               // 24 group-splits
  int blk = blockIdx.x % 60;
  int i = blk * 256 + threadIdx.x;        // output index 0..15359
  float a = 0.f;
#pragma unroll 8
  for (int g = gs * 32; g < gs * 32 + 32; ++g)
    a += partial[(size_t)g * 15360 + i];
  partial2[(size_t)gs * 15360 + i] = a;
}

__global__ __launch_bounds__(256) void k_reduceB(const float* __restrict__ partial2,
                                                 const float* __restrict__ bias,
                                                 float* __restrict__ outv) {
  int i = blockIdx.x * 256 + threadIdx.x;
  float a = bias[i % 120];
#pragma unroll
  for (int gs = 0; gs < RSPLIT; ++gs) a += partial2[(size_t)gs * 15360 + i];
  outv[i] = fmaxf(a, 0.f);  // relu fused
}

// ---------------- fc2 + fc3 + quantum head -> probs_conv (FROZEN) ----------------
__global__ __launch_bounds__(128) void k_head(const float* __restrict__ fc1o,
                                              const float* __restrict__ w2,
                                              const float* __restrict__ b2,
                                              const float* __restrict__ w3,
                                              const float* __restrict__ b3,
                                              const float* __restrict__ hth,
                                              float* __restrict__ probs_conv) {
  __shared__ float h1[120];
  __shared__ float h2[84];
  int b = blockIdx.x, tid = threadIdx.x;
  if (tid < 120) h1[tid] = fc1o[b * 120 + tid];
  __syncthreads();
  if (tid < 84) {
    float a = b2[tid];
    for (int k = 0; k < 120; ++k) a += h1[k] * w2[tid * 120 + k];
    h2[tid] = fmaxf(a, 0.f);
  }
  __syncthreads();
  if (tid == 0) {
    float lg = b3[0];
    for (int j = 0; j < 84; ++j) lg += h2[j] * w3[j];
    float s[16];
#pragma unroll
    for (int i = 0; i < 16; ++i) s[i] = 0.f;
    s[0] = 1.f;
    q_ry<0>(s, lg);
    q_layer(s, hth);
    float z = q_mz<0>(s);
    probs_conv[b] = 1.f / (1.f + expf(-z));
  }
}

// ---------------- resize 249->28 (jax linear+antialias) ----------------
DEV void resize_win(int o, int& i0, int& i1, float& sf, float& inorm) {
  const float invs = 249.0f / 28.0f;
  sf = ((float)o + 0.5f) * invs - 0.5f;
  i0 = (int)ceilf(sf - invs); if (i0 < 0) i0 = 0;
  i1 = (int)floorf(sf + invs); if (i1 > 248) i1 = 248;
  float nrm = 0.f;
  for (int i = i0; i <= i1; ++i)
    nrm += fmaxf(0.f, 1.f - fabsf(sf - (float)i) * (28.0f / 249.0f));
  inorm = 1.f / nrm;
}

// v3 row pass: READ-ONCE, 32-col groups x 8 iy-sublanes, 1024 blocks (kept)
__global__ __launch_bounds__(256) void k_resize1(const float* __restrict__ x,
                                                 float* __restrict__ tmp) {
  __shared__ float accs[8][28][32];    // 28.7 KB
  __shared__ float sf_t[28], inorm_t[28];
  int b = blockIdx.x >> 3, cg = blockIdx.x & 7;
  int tid = threadIdx.x;
  int iysub = tid >> 5, lane = tid & 31;
  int col = cg * 32 + lane;
  bool colok = col < 249;
  for (int i = tid; i < 8 * 28 * 32; i += 256) ((float*)accs)[i] = 0.f;
  if (tid < 28) {
    int i0, i1; float sf, inm;
    resize_win(tid, i0, i1, sf, inm);
    sf_t[tid] = sf; inorm_t[tid] = inm;
  }
  __syncthreads();
  const float* xb = x + (size_t)b * 186003;
  const float S = 28.0f / 249.0f;
  for (int it = 0; it < 32; ++it) {
    int iy = it * 8 + iysub;
    if (iy < 249 && colok) {
      int off = iy * 249 + col;
      float gray = (xb[off] + xb[62001 + off] + xb[124002 + off]) * (1.0f / 3.0f);
      float u = ((float)iy + 0.5f) * S;
      int oyh = (int)floorf(u + 0.5f);
#pragma unroll
      for (int d = 0; d < 2; ++d) {
        int oy = oyh - d;
        if (oy >= 0 && oy < 28) {
          float wv = fmaxf(0.f, 1.f - fabsf(sf_t[oy] - (float)iy) * S) * inorm_t[oy];
          accs[iysub][oy][lane] += wv * gray;
        }
      }
    }
  }
  __syncthreads();
  for (int i = tid; i < 28 * 32; i += 256) {
    int oy = i >> 5, c2 = i & 31;
    int colw = cg * 32 + c2;
    if (colw < 249) {
      float a = 0.f;
#pragma unroll
      for (int u2 = 0; u2 < 8; ++u2) a += accs[u2][oy][c2];
      tmp[((size_t)b * 28 + oy) * 249 + colw] = a;
    }
  }
}

// ---------------- col pass + patches + circuits (FROZEN) ----------------
__global__ __launch_bounds__(256) void k_quanv(const float* __restrict__ tmp,
                                               const float* __restrict__ qth,
                                               const float* __restrict__ lw,
                                               float* __restrict__ qpart) {
  __shared__ float g[392];
  __shared__ float red[4];
  int bid = blockIdx.x;
  int b = bid >> 1, half = bid & 1;
  int tid = threadIdx.x;
  for (int idx = tid; idx < 392; idx += 256) {
    int ly = idx / 28, ox = idx % 28;
    int oy = 14 * half + ly;
    int i0, i1; float sf, inorm;
    resize_win(ox, i0, i1, sf, inorm);
    const float* tr = tmp + ((size_t)b * 28 + oy) * 249;
    float acc = 0.f;
    for (int i = i0; i <= i1; ++i)
      acc += fmaxf(0.f, 1.f - fabsf(sf - (float)i) * (28.0f / 249.0f)) * inorm * tr[i];
    g[idx] = acc;
  }
  __syncthreads();
  float part = 0.f;
  if (tid < 98) {
    int pl = tid / 14, pj = tid % 14;
    int pi = 7 * half + pl;
    float v0 = g[(2 * pl) * 28 + 2 * pj];
    float v1 = g[(2 * pl) * 28 + 2 * pj + 1];
    float v2 = g[(2 * pl + 1) * 28 + 2 * pj];
    float v3 = g[(2 * pl + 1) * 28 + 2 * pj + 1];
    float s[16];
#pragma unroll
    for (int i = 0; i < 16; ++i) s[i] = 0.f;
    s[0] = 1.f;
    q_ry<0>(s, v0); q_ry<1>(s, v1); q_ry<2>(s, v2); q_ry<3>(s, v3);
    q_layer(s, qth);
    float z0 = q_mz<0>(s), z1 = q_mz<1>(s), z2 = q_mz<2>(s), z3 = q_mz<3>(s);
    const float* lwp = lw + (pi * 14 + pj) * 4;
    part = z0 * lwp[0] + z1 * lwp[1] + z2 * lwp[2] + z3 * lwp[3];
  }
#pragma unroll
  for (int off = 32; off > 0; off >>= 1) part += __shfl_down(part, off, 64);
  if ((tid & 63) == 0) red[tid >> 6] = part;
  __syncthreads();
  if (tid == 0) qpart[bid] = red[0] + red[1] + red[2] + red[3];
}

__global__ __launch_bounds__(128) void k_final(const float* __restrict__ qpart,
                                               const float* __restrict__ lb,
                                               const float* __restrict__ probs_conv,
                                               float* __restrict__ out) {
  int b = threadIdx.x;
  float tot = qpart[2 * b] + qpart[2 * b + 1] + lb[0];
  float pq = 1.f / (1.f + expf(-tot));
  float pr = 0.5f * (probs_conv[b] + pq);
  out[b * 2 + 0] = pr;
  out[b * 2 + 1] = 1.f - pr;
}

// ---------------- launch ----------------
extern "C" void kernel_launch(void* const* d_in, const int* in_sizes, int n_in,
                              void* d_out, int out_size, void* d_ws, size_t ws_size,
                              hipStream_t stream) {
  const float* x   = (const float*)d_in[0];
  const float* c1w = (const float*)d_in[1];
  const float* c1b = (const float*)d_in[2];
  const float* c2w = (const float*)d_in[3];
  const float* c2b = (const float*)d_in[4];
  const float* f1w = (const float*)d_in[5];
  const float* f1b = (const float*)d_in[6];
  const float* f2w = (const float*)d_in[7];
  const float* f2b = (const float*)d_in[8];
  const float* f3w = (const float*)d_in[9];
  const float* f3b = (const float*)d_in[10];
  const float* hth = (const float*)d_in[11];
  const float* qth = (const float*)d_in[12];
  const float* lw  = (const float*)d_in[13];
  const float* lb  = (const float*)d_in[14];
  float* out = (float*)d_out;
  char* ws = (char*)d_ws;

  // ws layout (bytes):
  //   [0, 48365568)   pool1 (128*6*123*128 f32, padded rows); dead after conv2.
  //     region reused: fc1 partials [0, 47185920) (768*15360 f32) — fully
  //     consumed by k_reduceA BEFORE k_resize1 writes tmp at [33554432, ...)
  //     (single-stream kernel order guarantees this).
  //   [33554432, 37124096)  tmp resize rows (written after reduceA)
  //   [48365568, 76942848)  h (128*55815 f32)
  //   [76942848, ...)       fc1o / pconv / wre1 / qpart
  //   [77012992, 78487552)  partial2 (24*15360 f32)
  float* pool1    = (float*)(ws);
  float* partial  = (float*)(ws);
  float* tmp      = (float*)(ws + 33554432);
  float* h        = (float*)(ws + 48365568);
  float* fc1o     = (float*)(ws + 76942848);
  float* pconv    = (float*)(ws + 77004288);
  float* wre1     = (float*)(ws + 77004800);
  float* qpart    = (float*)(ws + 77009848);
  float* partial2 = (float*)(ws + 77012992);

  k_wre<<<dim3(2), 256, 0, stream>>>(c1w, wre1);
  k_conv1<<<dim3(8, 3, 128), 256, 0, stream>>>(x, wre1, c1b, pool1);
  k_conv2<<<dim3(4, 4, 128), 256, 0, stream>>>(pool1, c2w, c2b, h);
  k_fc1<<<dim3(FC1_BLOCKS), 256, 0, stream>>>(h, f1w, partial);
  k_reduceA<<<dim3(RSPLIT * 60), 256, 0, stream>>>(partial, partial2);
  k_reduceB<<<dim3(60), 256, 0, stream>>>(partial2, f1b, fc1o);
  k_head<<<dim3(128), 128, 0, stream>>>(fc1o, f2w, f2b, f3w, f3b, hth, pconv);
  k_resize1<<<dim3(1024), 256, 0, stream>>>(x, tmp);
  k_quanv<<<dim3(256), 256, 0, stream>>>(tmp, qth, lw, qpart);
  k_final<<<dim3(1), 128, 0, stream>>>(qpart, lb, pconv, out);
}

// Round 22
// 238.956 us; speedup vs baseline: 1.0211x; 1.0211x over previous
//
#include <hip/hip_runtime.h>
#include <math.h>

#define DEV static __device__ __forceinline__

// ---------------- 4-qubit real-amplitude circuit helpers ----------------
template <int W>
DEV void q_ry(float s[16], float th) {
  float c = cosf(th * 0.5f), sn = sinf(th * 0.5f);
  constexpr int m = 8 >> W;
#pragma unroll
  for (int i = 0; i < 16; ++i) {
    if (!(i & m)) {
      float a = s[i], b = s[i | m];
      s[i] = c * a - sn * b;
      s[i | m] = sn * a + c * b;
    }
  }
}
template <int C, int T>
DEV void q_cnot(float s[16]) {
  constexpr int mc = 8 >> C, mt = 8 >> T;
#pragma unroll
  for (int i = 0; i < 16; ++i) {
    if ((i & mc) && !(i & mt)) {
      float t = s[i]; s[i] = s[i | mt]; s[i | mt] = t;
    }
  }
}
template <int W>
DEV float q_mz(const float s[16]) {
  constexpr int m = 8 >> W;
  float p = 0.f;
#pragma unroll
  for (int i = 0; i < 16; ++i) p += (i & m) ? -s[i] * s[i] : s[i] * s[i];
  return p;
}
DEV void q_layer(float s[16], const float* __restrict__ th) {
  q_ry<0>(s, th[0]); q_cnot<0, 1>(s);
  q_ry<1>(s, th[1]); q_cnot<1, 2>(s);
  q_ry<2>(s, th[2]); q_cnot<2, 3>(s);
  q_ry<3>(s, th[3]); q_cnot<3, 0>(s);
}

// ---------------- weight reorder pre-kernel (conv1 only) ----------------
__global__ void k_wre(const float* __restrict__ c1w, float* __restrict__ wre1) {
  int t = blockIdx.x * 256 + threadIdx.x;
  if (t < 450) {
    int g = t / 30, rem = t % 30;
    int ci = g / 5, ky = g % 5, kx = rem / 6, co = rem % 6;
    wre1[t] = c1w[co * 75 + ci * 25 + ky * 5 + kx];
  }
}

// row base with parity rotation
DEV int c1_rowbase(int row) { return row * 39 + ((row >> 1) & 1); }

// ---------------- conv1 (5x5 s2 p1, 3->6) + relu + pool(2x2 s1) ----------------
// v8 (FROZEN — proven best at 112us / 240.9 total). Register budget exactly
// full at 60 VGPR; all async/occupancy variants spilled. Structure floor.
// x: (128,3,249,249) -> pooled out: (128,6,123,[128])
__global__ __launch_bounds__(256, 4) void k_conv1(const float* __restrict__ x,
                                                  const float* __restrict__ wre1,
                                                  const float* __restrict__ bia,
                                                  float* __restrict__ out) {
  __shared__ float smem[4800];
  float (*ct)[42][19] = (float (*)[42][19])smem;
  int b = blockIdx.z;
  int PY0 = blockIdx.y * 41, PX0 = blockIdx.x * 16;
  int iy0 = PY0 * 2 - 1, ix0 = PX0 * 2 - 1;
  int tid = threadIdx.x;
  const float* xb = x + (size_t)b * 186003;
  int r = tid / 6, seg = tid - 6 * (tid / 6);
  float acc[6][3];
#pragma unroll
  for (int co = 0; co < 6; ++co) {
    float bv = bia[co];
#pragma unroll
    for (int c = 0; c < 3; ++c) acc[co][c] = bv;
  }
#pragma unroll 1
  for (int ci = 0; ci < 3; ++ci) {
    if (ci) __syncthreads();
    const float* xci = xb + ci * 62001;
#pragma unroll
    for (int s = 0; s < 14; ++s) {
      int idx = s * 256 + tid;
      bool ok = idx < 3393;
      int rr = idx / 39, cc = idx - rr * 39;
      int iy = iy0 + rr, ix = ix0 + cc;
      float v = 0.f;
      if (ok && cc < 37 && (unsigned)iy < 249u && (unsigned)ix < 249u)
        v = xci[iy * 249 + ix];
      if (ok && cc < 37) smem[c1_rowbase(rr) + cc] = v;
    }
    __syncthreads();
    if (tid < 252) {
#pragma unroll
      for (int ky = 0; ky < 5; ++ky) {
        const float* xrow = &smem[c1_rowbase(2 * r + ky) + 6 * seg];
        float xv[10];
#pragma unroll
        for (int j = 0; j < 10; ++j) xv[j] = xrow[j];
        const float* wp = wre1 + (ci * 5 + ky) * 30;
        float wr[30];
#pragma unroll
        for (int j = 0; j < 30; ++j) wr[j] = wp[j];
#pragma unroll
        for (int c = 0; c < 3; ++c)
#pragma unroll
          for (int kx = 0; kx < 5; ++kx)
#pragma unroll
            for (int co = 0; co < 6; ++co)
              acc[co][c] += xv[2 * c + kx] * wr[kx * 6 + co];
      }
    }
  }
  __syncthreads();
  if (tid < 252) {
#pragma unroll
    for (int co = 0; co < 6; ++co)
#pragma unroll
      for (int c = 0; c < 3; ++c)
        if (3 * seg + c < 17) ct[co][r][3 * seg + c] = acc[co][c];
  }
  __syncthreads();
#pragma unroll
  for (int co2 = 0; co2 < 6; ++co2) {
    for (int j = tid; j < 41 * 16; j += 256) {
      int pr = j >> 4, pc = j & 15;
      float m = fmaxf(fmaxf(ct[co2][pr][pc], ct[co2][pr][pc + 1]),
                      fmaxf(ct[co2][pr + 1][pc], ct[co2][pr + 1][pc + 1]));
      out[((size_t)(b * 6 + co2) * 123 + PY0 + pr) * 128 + PX0 + pc] = fmaxf(m, 0.f);
    }
  }
}

// ---------------- conv2 (3x3 s2 p1, 6->15) + relu + pool (FROZEN) ----------------
__global__ __launch_bounds__(256, 4) void k_conv2(const float* __restrict__ in,
                                                  const float* __restrict__ w,
                                                  const float* __restrict__ bia,
                                                  float* __restrict__ out) {
  __shared__ float smem[6 * 35 * 36];
  float (*xs)[35][36] = (float (*)[35][36])smem;
  float (*ct)[17][18] = (float (*)[17][18])smem;
  int b = blockIdx.z;
  int py0 = blockIdx.y * 16, px0 = blockIdx.x * 16;
  int iy0 = py0 * 2 - 1, ix0 = px0 * 2 - 1;
  int tid = threadIdx.x;
  const float* ib = in + (size_t)b * 94464;
  for (int idx = tid; idx < 6 * 35 * 36; idx += 256) {
    int ci = idx / 1260, rem = idx % 1260, rr = rem / 36, cc = rem % 36;
    int iy = iy0 + rr, ix = ix0 + cc;
    float v = 0.f;
    if (cc < 35 && (unsigned)iy < 123u && (unsigned)ix < 123u)
      v = ib[ci * 15744 + iy * 128 + ix];
    xs[ci][rr][cc] = v;
  }
  __syncthreads();
  int co = tid % 15, ty = tid / 15;
  float acc[17];
  if (tid < 255) {
    float bv = bia[co];
#pragma unroll
    for (int t = 0; t < 17; ++t) acc[t] = bv;
#pragma unroll
    for (int ci = 0; ci < 6; ++ci) {
      float wreg[9];
#pragma unroll
      for (int j = 0; j < 9; ++j) wreg[j] = w[co * 54 + ci * 9 + j];
#pragma unroll
      for (int ky = 0; ky < 3; ++ky) {
        const float* xrow = &xs[ci][2 * ty + ky][0];
        float xv[36];
#pragma unroll
        for (int j = 0; j < 18; ++j) {
          float2 t2 = *reinterpret_cast<const float2*>(&xrow[2 * j]);
          xv[2 * j] = t2.x; xv[2 * j + 1] = t2.y;
        }
#pragma unroll
        for (int tx = 0; tx < 17; ++tx)
#pragma unroll
          for (int kx = 0; kx < 3; ++kx)
            acc[tx] += xv[2 * tx + kx] * wreg[ky * 3 + kx];
      }
    }
  }
  __syncthreads();
  if (tid < 255) {
#pragma unroll
    for (int tx = 0; tx < 17; ++tx) ct[co][ty][tx] = acc[tx];
  }
  __syncthreads();
  for (int i = tid; i < 15 * 16 * 16; i += 256) {
    int co2 = i / 256, rem = i % 256, pr = rem / 16, pc = rem % 16;
    int py = py0 + pr, px = px0 + pc;
    if (py < 61 && px < 61) {
      float m = fmaxf(fmaxf(ct[co2][pr][pc], ct[co2][pr][pc + 1]),
                      fmaxf(ct[co2][pr + 1][pc], ct[co2][pr + 1][pc + 1]));
      out[(size_t)b * 55815 + co2 * 3721 + py * 61 + px] = fmaxf(m, 0.f);
    }
  }
}

// ---------------- fc1 (round-14 body, 768 blocks — proven round 20) -------------
#define KFC 55815
#define NCHUNK 1745  // ceil(55815/32)
#define FC1_BLOCKS 768
#define RSPLIT 24    // FC1_BLOCKS / 32
__global__ __launch_bounds__(256) void k_fc1(const float* __restrict__ h,
                                             const float* __restrict__ w,
                                             float* __restrict__ partial) {
  __shared__ float hs[128][33];   // +1 pad
  __shared__ float wsd[120][33];
  int tid = threadIdx.x;
  int tb = tid & 31;   // batch lane
  int bo = tid >> 5;   // output group: outputs bo*15 .. bo*15+14
  float acc[4][15];
#pragma unroll
  for (int j = 0; j < 4; ++j)
#pragma unroll
    for (int oo = 0; oo < 15; ++oo) acc[j][oo] = 0.f;

  for (int ch = blockIdx.x; ch < NCHUNK; ch += FC1_BLOCKS) {
    int k0 = ch * 32;
    for (int idx = tid; idx < 128 * 32; idx += 256) {
      int bb = idx >> 5, kk = idx & 31;
      int k = k0 + kk;
      hs[bb][kk] = (k < KFC) ? h[(size_t)bb * KFC + k] : 0.f;
    }
    for (int idx = tid; idx < 120 * 32; idx += 256) {
      int oo = idx >> 5, kk = idx & 31;
      int k = k0 + kk;
      wsd[oo][kk] = (k < KFC) ? w[(size_t)oo * KFC + k] : 0.f;
    }
    __syncthreads();
#pragma unroll 4
    for (int kk = 0; kk < 32; ++kk) {
      float hv[4], wv[15];
#pragma unroll
      for (int j = 0; j < 4; ++j) hv[j] = hs[tb + 32 * j][kk];
#pragma unroll
      for (int oo = 0; oo < 15; ++oo) wv[oo] = wsd[bo * 15 + oo][kk];
#pragma unroll
      for (int j = 0; j < 4; ++j)
#pragma unroll
        for (int oo = 0; oo < 15; ++oo) acc[j][oo] += hv[j] * wv[oo];
    }
    __syncthreads();
  }
  float* pg = partial + (size_t)blockIdx.x * 15360;
#pragma unroll
  for (int j = 0; j < 4; ++j) {
    int b = tb + 32 * j;
#pragma unroll
    for (int oo = 0; oo < 15; ++oo) pg[b * 120 + bo * 15 + oo] = acc[j][oo];
  }
}

// ---------------- fc1 reduce stage A (kept) -------------------------------------
__global__ __launch_bounds__(256) void k_reduceA(const float* __restrict__ partial,
                                                 float* __restrict__ partial2) {
  int gs = blockIdx.x / 60;               // 24 group-splits
  int blk = blockIdx.x % 60;
  int i = blk * 256 + threadIdx.x;        // output index 0..15359
  float a = 0.f;
#pragma unroll 8
  for (int g = gs * 32; g < gs * 32 + 32; ++g)
    a += partial[(size_t)g * 15360 + i];
  partial2[(size_t)gs * 15360 + i] = a;
}

// ---------------- head v2: reduceB MERGED + fc2 + fc3 + circuit -----------------
// Block b: 120 lanes finish the fc1 reduction for this batch (24 coalesced
// strided loads each), relu; then fc2/fc3/4-qubit head as before.
__global__ __launch_bounds__(128) void k_head(const float* __restrict__ partial2,
                                              const float* __restrict__ b1,
                                              const float* __restrict__ w2,
                                              const float* __restrict__ b2,
                                              const float* __restrict__ w3,
                                              const float* __restrict__ b3,
                                              const float* __restrict__ hth,
                                              float* __restrict__ probs_conv) {
  __shared__ float h1[120];
  __shared__ float h2[84];
  int b = blockIdx.x, tid = threadIdx.x;
  if (tid < 120) {
    float a = b1[tid];
#pragma unroll
    for (int gs = 0; gs < RSPLIT; ++gs)
      a += partial2[(size_t)gs * 15360 + b * 120 + tid];
    h1[tid] = fmaxf(a, 0.f);
  }
  __syncthreads();
  if (tid < 84) {
    float a = b2[tid];
    for (int k = 0; k < 120; ++k) a += h1[k] * w2[tid * 120 + k];
    h2[tid] = fmaxf(a, 0.f);
  }
  __syncthreads();
  if (tid == 0) {
    float lg = b3[0];
    for (int j = 0; j < 84; ++j) lg += h2[j] * w3[j];
    float s[16];
#pragma unroll
    for (int i = 0; i < 16; ++i) s[i] = 0.f;
    s[0] = 1.f;
    q_ry<0>(s, lg);
    q_layer(s, hth);
    float z = q_mz<0>(s);
    probs_conv[b] = 1.f / (1.f + expf(-z));
  }
}

// ---------------- resize 249->28 (jax linear+antialias) ----------------
DEV void resize_win(int o, int& i0, int& i1, float& sf, float& inorm) {
  const float invs = 249.0f / 28.0f;
  sf = ((float)o + 0.5f) * invs - 0.5f;
  i0 = (int)ceilf(sf - invs); if (i0 < 0) i0 = 0;
  i1 = (int)floorf(sf + invs); if (i1 > 248) i1 = 248;
  float nrm = 0.f;
  for (int i = i0; i <= i1; ++i)
    nrm += fmaxf(0.f, 1.f - fabsf(sf - (float)i) * (28.0f / 249.0f));
  inorm = 1.f / nrm;
}

// v3 row pass: READ-ONCE, 32-col groups x 8 iy-sublanes, 1024 blocks (kept)
__global__ __launch_bounds__(256) void k_resize1(const float* __restrict__ x,
                                                 float* __restrict__ tmp) {
  __shared__ float accs[8][28][32];    // 28.7 KB
  __shared__ float sf_t[28], inorm_t[28];
  int b = blockIdx.x >> 3, cg = blockIdx.x & 7;
  int tid = threadIdx.x;
  int iysub = tid >> 5, lane = tid & 31;
  int col = cg * 32 + lane;
  bool colok = col < 249;
  for (int i = tid; i < 8 * 28 * 32; i += 256) ((float*)accs)[i] = 0.f;
  if (tid < 28) {
    int i0, i1; float sf, inm;
    resize_win(tid, i0, i1, sf, inm);
    sf_t[tid] = sf; inorm_t[tid] = inm;
  }
  __syncthreads();
  const float* xb = x + (size_t)b * 186003;
  const float S = 28.0f / 249.0f;
  for (int it = 0; it < 32; ++it) {
    int iy = it * 8 + iysub;
    if (iy < 249 && colok) {
      int off = iy * 249 + col;
      float gray = (xb[off] + xb[62001 + off] + xb[124002 + off]) * (1.0f / 3.0f);
      float u = ((float)iy + 0.5f) * S;
      int oyh = (int)floorf(u + 0.5f);
#pragma unroll
      for (int d = 0; d < 2; ++d) {
        int oy = oyh - d;
        if (oy >= 0 && oy < 28) {
          float wv = fmaxf(0.f, 1.f - fabsf(sf_t[oy] - (float)iy) * S) * inorm_t[oy];
          accs[iysub][oy][lane] += wv * gray;
        }
      }
    }
  }
  __syncthreads();
  for (int i = tid; i < 28 * 32; i += 256) {
    int oy = i >> 5, c2 = i & 31;
    int colw = cg * 32 + c2;
    if (colw < 249) {
      float a = 0.f;
#pragma unroll
      for (int u2 = 0; u2 < 8; ++u2) a += accs[u2][oy][c2];
      tmp[((size_t)b * 28 + oy) * 249 + colw] = a;
    }
  }
}

// ---------------- col pass + patches + circuits (FROZEN) ----------------
__global__ __launch_bounds__(256) void k_quanv(const float* __restrict__ tmp,
                                               const float* __restrict__ qth,
                                               const float* __restrict__ lw,
                                               float* __restrict__ qpart) {
  __shared__ float g[392];
  __shared__ float red[4];
  int bid = blockIdx.x;
  int b = bid >> 1, half = bid & 1;
  int tid = threadIdx.x;
  for (int idx = tid; idx < 392; idx += 256) {
    int ly = idx / 28, ox = idx % 28;
    int oy = 14 * half + ly;
    int i0, i1; float sf, inorm;
    resize_win(ox, i0, i1, sf, inorm);
    const float* tr = tmp + ((size_t)b * 28 + oy) * 249;
    float acc = 0.f;
    for (int i = i0; i <= i1; ++i)
      acc += fmaxf(0.f, 1.f - fabsf(sf - (float)i) * (28.0f / 249.0f)) * inorm * tr[i];
    g[idx] = acc;
  }
  __syncthreads();
  float part = 0.f;
  if (tid < 98) {
    int pl = tid / 14, pj = tid % 14;
    int pi = 7 * half + pl;
    float v0 = g[(2 * pl) * 28 + 2 * pj];
    float v1 = g[(2 * pl) * 28 + 2 * pj + 1];
    float v2 = g[(2 * pl + 1) * 28 + 2 * pj];
    float v3 = g[(2 * pl + 1) * 28 + 2 * pj + 1];
    float s[16];
#pragma unroll
    for (int i = 0; i < 16; ++i) s[i] = 0.f;
    s[0] = 1.f;
    q_ry<0>(s, v0); q_ry<1>(s, v1); q_ry<2>(s, v2); q_ry<3>(s, v3);
    q_layer(s, qth);
    float z0 = q_mz<0>(s), z1 = q_mz<1>(s), z2 = q_mz<2>(s), z3 = q_mz<3>(s);
    const float* lwp = lw + (pi * 14 + pj) * 4;
    part = z0 * lwp[0] + z1 * lwp[1] + z2 * lwp[2] + z3 * lwp[3];
  }
#pragma unroll
  for (int off = 32; off > 0; off >>= 1) part += __shfl_down(part, off, 64);
  if ((tid & 63) == 0) red[tid >> 6] = part;
  __syncthreads();
  if (tid == 0) qpart[bid] = red[0] + red[1] + red[2] + red[3];
}

__global__ __launch_bounds__(128) void k_final(const float* __restrict__ qpart,
                                               const float* __restrict__ lb,
                                               const float* __restrict__ probs_conv,
                                               float* __restrict__ out) {
  int b = threadIdx.x;
  float tot = qpart[2 * b] + qpart[2 * b + 1] + lb[0];
  float pq = 1.f / (1.f + expf(-tot));
  float pr = 0.5f * (probs_conv[b] + pq);
  out[b * 2 + 0] = pr;
  out[b * 2 + 1] = 1.f - pr;
}

// ---------------- launch ----------------
extern "C" void kernel_launch(void* const* d_in, const int* in_sizes, int n_in,
                              void* d_out, int out_size, void* d_ws, size_t ws_size,
                              hipStream_t stream) {
  const float* x   = (const float*)d_in[0];
  const float* c1w = (const float*)d_in[1];
  const float* c1b = (const float*)d_in[2];
  const float* c2w = (const float*)d_in[3];
  const float* c2b = (const float*)d_in[4];
  const float* f1w = (const float*)d_in[5];
  const float* f1b = (const float*)d_in[6];
  const float* f2w = (const float*)d_in[7];
  const float* f2b = (const float*)d_in[8];
  const float* f3w = (const float*)d_in[9];
  const float* f3b = (const float*)d_in[10];
  const float* hth = (const float*)d_in[11];
  const float* qth = (const float*)d_in[12];
  const float* lw  = (const float*)d_in[13];
  const float* lb  = (const float*)d_in[14];
  float* out = (float*)d_out;
  char* ws = (char*)d_ws;

  // ws layout (bytes):
  //   [0, 48365568)   pool1 (128*6*123*128 f32, padded rows); dead after conv2.
  //     region reused: fc1 partials [0, 47185920) (768*15360 f32) — fully
  //     consumed by k_reduceA BEFORE k_resize1 writes tmp at [33554432, ...)
  //     (single-stream kernel order guarantees this).
  //   [33554432, 37124096)  tmp resize rows (written after reduceA)
  //   [48365568, 76942848)  h (128*55815 f32)
  //   [76942848, ...)       fc1o(unused now) / pconv / wre1 / qpart
  //   [77012992, 78487552)  partial2 (24*15360 f32)
  float* pool1    = (float*)(ws);
  float* partial  = (float*)(ws);
  float* tmp      = (float*)(ws + 33554432);
  float* h        = (float*)(ws + 48365568);
  float* pconv    = (float*)(ws + 77004288);
  float* wre1     = (float*)(ws + 77004800);
  float* qpart    = (float*)(ws + 77009848);
  float* partial2 = (float*)(ws + 77012992);

  k_wre<<<dim3(2), 256, 0, stream>>>(c1w, wre1);
  k_conv1<<<dim3(8, 3, 128), 256, 0, stream>>>(x, wre1, c1b, pool1);
  k_conv2<<<dim3(4, 4, 128), 256, 0, stream>>>(pool1, c2w, c2b, h);
  k_fc1<<<dim3(FC1_BLOCKS), 256, 0, stream>>>(h, f1w, partial);
  k_reduceA<<<dim3(RSPLIT * 60), 256, 0, stream>>>(partial, partial2);
  k_head<<<dim3(128), 128, 0, stream>>>(partial2, f1b, f2w, f2b, f3w, f3b, hth, pconv);
  k_resize1<<<dim3(1024), 256, 0, stream>>>(x, tmp);
  k_quanv<<<dim3(256), 256, 0, stream>>>(tmp, qth, lw, qpart);
  k_final<<<dim3(1), 128, 0, stream>>>(qpart, lb, pconv, out);
}